// Round 13
// baseline (261.247 us; speedup 1.0000x reference)
//
#include <hip/hip_runtime.h>
#include <cstdint>

typedef __attribute__((ext_vector_type(8))) __bf16 bf16x8;
typedef __attribute__((ext_vector_type(4))) float f32x4;
typedef __attribute__((ext_vector_type(8))) unsigned short u16x8;
typedef __attribute__((ext_vector_type(4))) unsigned short u16x4;

__device__ __forceinline__ unsigned short f2bf(float f) {
    union { float f; unsigned u; } v; v.f = f;
    unsigned u = v.u;
    return (unsigned short)((u + 0x7FFFu + ((u >> 16) & 1u)) >> 16);
}

__device__ __forceinline__ void gload_lds16(const void* g, void* l) {
    auto gp = reinterpret_cast<__attribute__((address_space(1))) unsigned*>(
        reinterpret_cast<uintptr_t>(g));
    auto lp = reinterpret_cast<__attribute__((address_space(3))) unsigned*>(
        reinterpret_cast<uintptr_t>(l));
    __builtin_amdgcn_global_load_lds(gp, lp, 16, 0, 0);
}

// ---------------- fused prep: cvt x | cvt latents | W transposes (one launch) ----------------
__global__ __launch_bounds__(256) void prep(const float* __restrict__ x,
                                            const float* __restrict__ latents,
                                            const float* __restrict__ Wq,
                                            const float* __restrict__ Wkv,
                                            const float* __restrict__ Wout,
                                            unsigned short* __restrict__ xb,
                                            unsigned short* __restrict__ latb,
                                            unsigned short* __restrict__ wqkvt,
                                            unsigned short* __restrict__ wkvt,
                                            unsigned short* __restrict__ woutt) {
    int b = blockIdx.x, tid = threadIdx.x;
    if (b < 2048) {                       // cvt x: 33554432 elems = 8388608 float4
        int idx = b * 256 + tid, stride = 2048 * 256;
        for (int i = idx; i < 8388608; i += stride) {
            float4 v = ((const float4*)x)[i];
            u16x4 o;
            o.x = f2bf(v.x); o.y = f2bf(v.y); o.z = f2bf(v.z); o.w = f2bf(v.w);
            ((u16x4*)xb)[i] = o;
        }
        return;
    }
    b -= 2048;
    if (b < 64) {                         // cvt latents: 16384 float4
        int i = b * 256 + tid;
        float4 v = ((const float4*)latents)[i];
        u16x4 o;
        o.x = f2bf(v.x); o.y = f2bf(v.y); o.z = f2bf(v.z); o.w = f2bf(v.w);
        ((u16x4*)latb)[i] = o;
        return;
    }
    b -= 64;
    const float* in; unsigned short* out; int R, C, bx, by;
    if (b < 1024)      { in = Wq;   out = wqkvt; R = 1024; C = 1024; bx = b & 31; by = b >> 5; }
    else if (b < 3072) { int v = b - 1024; in = Wkv;  out = wkvt;  R = 1024; C = 2048; bx = v & 63; by = v >> 6; }
    else               { int v = b - 3072; in = Wout; out = woutt; R = 1024; C = 1024; bx = v & 31; by = v >> 5; }
    __shared__ float t[32][33];
    int c0 = bx * 32, r0 = by * 32;
    int tx = tid & 31, ty = tid >> 5;
    for (int i = ty; i < 32; i += 8)
        t[i][tx] = in[(size_t)(r0 + i) * C + c0 + tx];
    __syncthreads();
    for (int i = ty; i < 32; i += 8)
        out[(size_t)(c0 + i) * R + r0 + tx] = f2bf(t[tx][i]);
}

// ---------------- pipelined 128x128 bf16 GEMM body (triple-buffer, counted vmcnt) ----
// tid is a VIRTUAL 256-thread id (512-thread callers pass tid&255: waves 4-7 mirror 0-3 —
// duplicate DMA/stores of identical data to identical addresses, barrier-safe).
__device__ __forceinline__ void gemm128p_body(const unsigned short* __restrict__ A,
                                              const unsigned short* __restrict__ Bt,
                                              void* __restrict__ C,
                                              const float* __restrict__ bias,
                                              unsigned short* __restrict__ vT,
                                              int M, int N, int K, float scale, int split,
                                              int c_f32, int vstart,
                                              int tid, int bid, int nwg,
                                              unsigned short* ldsbuf) {
#define LDSP(bi, half) (ldsbuf + ((bi) * 2 + (half)) * 4096)
    int ntx = N >> 7;
    int swz = bid;
    if ((nwg & 7) == 0) { int cpx = nwg >> 3; swz = (bid & 7) * cpx + (bid >> 3); }
    int m0 = (swz / ntx) << 7, n0 = (swz % ntx) << 7;
    int lane = tid & 63, w = tid >> 6;
    int wm = w >> 1, wn = w & 1;
    int lr = lane & 15, lg = lane >> 4;
    int gq = lg ^ ((lr >> 1) & 3);
    int nkt = K >> 5;

    int arow = tid >> 2;
    int sgl = (tid & 3) ^ ((arow >> 1) & 3);
    int ra0 = m0 + arow;      if (ra0 > M - 1) ra0 = M - 1;
    int ra1 = m0 + 64 + arow; if (ra1 > M - 1) ra1 = M - 1;
    const unsigned short* a0 = A + (size_t)ra0 * K + (sgl << 3);
    const unsigned short* a1 = A + (size_t)ra1 * K + (sgl << 3);
    const unsigned short* b0 = Bt + (size_t)(n0 + arow) * K + (sgl << 3);
    const unsigned short* b1 = Bt + (size_t)(n0 + 64 + arow) * K + (sgl << 3);

    f32x4 acc[4][4] = {};

#define ST_A128(bi, kt) do { \
        gload_lds16(a0 + ((kt) << 5), LDSP(bi, 0) + (w << 9)); \
        gload_lds16(a1 + ((kt) << 5), LDSP(bi, 0) + 2048 + (w << 9)); } while (0)
#define ST_B128(bi, kt) do { \
        gload_lds16(b0 + ((kt) << 5), LDSP(bi, 1) + (w << 9)); \
        gload_lds16(b1 + ((kt) << 5), LDSP(bi, 1) + 2048 + (w << 9)); } while (0)

    ST_A128(0, 0); ST_B128(0, 0);
    ST_A128(1, 1); ST_B128(1, 1);

    int buf = 0;
    for (int t = 0; t < nkt; ++t) {
        asm volatile("s_waitcnt vmcnt(4) lgkmcnt(0)" ::: "memory");
        __builtin_amdgcn_sched_barrier(0);
        __builtin_amdgcn_s_barrier();
        __builtin_amdgcn_sched_barrier(0);
        int st = t + 2; if (st >= nkt) st = nkt - 1;
        int sbuf = buf + 2; if (sbuf >= 3) sbuf -= 3;
        ST_A128(sbuf, st);
        ST_B128(sbuf, st);
        const unsigned short* pa = LDSP(buf, 0) + ((wm << 6) + lr) * 32 + (gq << 3);
        const unsigned short* pb = LDSP(buf, 1) + ((wn << 6) + lr) * 32 + (gq << 3);
        bf16x8 af[4], bfr[4];
#pragma unroll
        for (int nt = 0; nt < 4; nt++) bfr[nt] = *(const bf16x8*)(pb + nt * 512);
#pragma unroll
        for (int mt = 0; mt < 4; mt++) af[mt] = *(const bf16x8*)(pa + mt * 512);
        __builtin_amdgcn_s_setprio(1);
#pragma unroll
        for (int mt = 0; mt < 4; mt++)
#pragma unroll
            for (int nt = 0; nt < 4; nt++)
                acc[mt][nt] = __builtin_amdgcn_mfma_f32_16x16x32_bf16(af[mt], bfr[nt], acc[mt][nt], 0, 0, 0);
        __builtin_amdgcn_s_setprio(0);
        buf++; if (buf == 3) buf = 0;
    }
#undef ST_A128
#undef ST_B128
#undef LDSP

#pragma unroll
    for (int mt = 0; mt < 4; mt++) {
#pragma unroll
        for (int nt = 0; nt < 4; nt++) {
            int col = n0 + (wn << 6) + (nt << 4) + lr;
            float sc = (col < split) ? scale : 1.0f;
            float bv = bias ? bias[col] : 0.0f;
#pragma unroll
            for (int r = 0; r < 4; r++) {
                int row = m0 + (wm << 6) + (mt << 4) + (lg << 2) + r;
                if (row < M) {
                    float v = acc[mt][nt][r] * sc + bv;
                    if (vT && col >= vstart) vT[(size_t)(col - vstart) * 64 + row] = f2bf(v);
                    else if (c_f32) ((float*)C)[(size_t)row * N + col] = v;
                    else ((unsigned short*)C)[(size_t)row * N + col] = f2bf(v);
                }
            }
        }
    }
}

__global__ __launch_bounds__(256) void gemm128p(const unsigned short* __restrict__ A,
                                                const unsigned short* __restrict__ Bt,
                                                void* __restrict__ C,
                                                const float* __restrict__ bias,
                                                unsigned short* __restrict__ vT,
                                                int M, int N, int K, float scale, int split,
                                                int c_f32, int vstart) {
    __shared__ unsigned short lds[3 * 2 * 4096];
    gemm128p_body(A, Bt, C, bias, vT, M, N, K, scale, split, c_f32, vstart,
                  threadIdx.x, blockIdx.x, gridDim.x, lds);
}

// ---------------- mega: [0,24) qlkv gemm | [24,1048) 256x256 BK=32 GEMM ----------------
// kv GEMM: m201-style per-phase barrier PAIRS. Triple-buffer (3 x 32 KiB), BK=32,
// 2 phases/K-tile, each phase {ds_reads; BAR; lgkm0; setprio 16 MFMA; BAR}.
// PROLOGUE FIX (r12 NaN): stage tiles 0,1 then {vmcnt(4); barrier} — drains tile 0 for
// ALL waves before any pre-barrier read of buf0 (m201's vmcnt+barrier prologue pattern).
// Loop-top vmcnt(4) at t then drains tile t+1 exactly (tile t+2 stays in flight; never 0).
// Overwrite of buf b (tile t+2) issues only after the closing barrier that follows every
// wave's lgkm0 for its last reads of b (tile t-1).
__global__ __launch_bounds__(512, 2) void mega(const unsigned short* __restrict__ latb,
                                               const unsigned short* __restrict__ wqkvt,
                                               unsigned short* __restrict__ qlkvb,
                                               unsigned short* __restrict__ lvT,
                                               const unsigned short* __restrict__ A,
                                               const unsigned short* __restrict__ Bt,
                                               unsigned short* __restrict__ kb,
                                               unsigned short* __restrict__ vbT,
                                               int M, int N, int K) {
    __shared__ unsigned short lds[3][16384];  // 3 bufs x [A: 256x32 | B: 256x32] = 96 KiB

    if (blockIdx.x < 24) {
        gemm128p_body(latb, wqkvt, qlkvb, nullptr, lvT, 64, 3072, 1024, 0.125f, 1024, 0, 2048,
                      threadIdx.x & 255, blockIdx.x, 24, &lds[0][0]);
        return;
    }

    int nkt = K >> 5;  // BK=32
    int ntx = N >> 8;
    int nwg = (M >> 8) * (N >> 8);
    int bid = blockIdx.x - 24, swz = bid;
    if ((nwg & 7) == 0) { int cpx = nwg >> 3; swz = (bid & 7) * cpx + (bid >> 3); }
    int m0 = (swz / ntx) << 8, n0 = (swz % ntx) << 8;
    int tid = threadIdx.x, lane = tid & 63, w = tid >> 6;
    int wm = w >> 2, wn = w & 3;
    int lr = lane & 15, lg = lane >> 4;
    int gq = lg ^ ((lr >> 1) & 3);

    // staging (r2-verified): thread covers plane row tid>>2, phys granule tid&3,
    // inverse-swizzled global granule sgl.
    int srow = tid >> 2;
    int sgl = (tid & 3) ^ ((srow >> 1) & 3);
    const unsigned short* a0 = A + (size_t)(m0 + srow) * K + (sgl << 3);
    const unsigned short* a1 = A + (size_t)(m0 + 128 + srow) * K + (sgl << 3);
    const unsigned short* b0 = Bt + (size_t)(n0 + srow) * K + (sgl << 3);
    const unsigned short* b1 = Bt + (size_t)(n0 + 128 + srow) * K + (sgl << 3);

    f32x4 acc[8][4] = {};

#define ST32(bi, kt) do { \
        gload_lds16(a0 + ((kt) << 5), &lds[bi][w << 9]); \
        gload_lds16(a1 + ((kt) << 5), &lds[bi][4096 + (w << 9)]); \
        gload_lds16(b0 + ((kt) << 5), &lds[bi][8192 + (w << 9)]); \
        gload_lds16(b1 + ((kt) << 5), &lds[bi][12288 + (w << 9)]); } while (0)

    // prologue: tiles 0,1 staged; drain tile 0 (leave tile 1 counted) + publish barrier
    ST32(0, 0);
    ST32(1, 1);
    asm volatile("s_waitcnt vmcnt(4)" ::: "memory");
    __builtin_amdgcn_s_barrier();
    __builtin_amdgcn_sched_barrier(0);

    int cur = 0;
    for (int t = 0; t < nkt; ++t) {
        int st = t + 2; if (st >= nkt) st = nkt - 1;   // clamp keeps counts uniform
        int sbuf = cur + 2; if (sbuf >= 3) sbuf -= 3;

        // ---- P0: stage tile t+2; vmcnt(4) drains tile t+1; reads m0-3 + B; BAR; MFMA ----
        ST32(sbuf, st);
        __builtin_amdgcn_sched_barrier(0);
        asm volatile("s_waitcnt vmcnt(4)" ::: "memory");
        __builtin_amdgcn_sched_barrier(0);
        const unsigned short* pa = &lds[cur][((wm << 7) + lr) * 32 + (gq << 3)];
        const unsigned short* pb = &lds[cur][8192 + ((wn << 6) + lr) * 32 + (gq << 3)];
        bf16x8 af[4], bfr[4];
#pragma unroll
        for (int nt = 0; nt < 4; nt++) bfr[nt] = *(const bf16x8*)(pb + nt * 512);
#pragma unroll
        for (int i = 0; i < 4; i++) af[i] = *(const bf16x8*)(pa + i * 512);
        __builtin_amdgcn_s_barrier();
        asm volatile("s_waitcnt lgkmcnt(0)" ::: "memory");
        __builtin_amdgcn_sched_barrier(0);
        __builtin_amdgcn_s_setprio(1);
#pragma unroll
        for (int i = 0; i < 4; i++)
#pragma unroll
            for (int nt = 0; nt < 4; nt++)
                acc[i][nt] = __builtin_amdgcn_mfma_f32_16x16x32_bf16(af[i], bfr[nt], acc[i][nt], 0, 0, 0);
        __builtin_amdgcn_s_setprio(0);
        __builtin_amdgcn_s_barrier();

        // ---- P1: reads m4-7; BAR; MFMA; closing BAR ----
#pragma unroll
        for (int i = 0; i < 4; i++) af[i] = *(const bf16x8*)(pa + (i + 4) * 512);
        __builtin_amdgcn_s_barrier();
        asm volatile("s_waitcnt lgkmcnt(0)" ::: "memory");
        __builtin_amdgcn_sched_barrier(0);
        __builtin_amdgcn_s_setprio(1);
#pragma unroll
        for (int i = 0; i < 4; i++)
#pragma unroll
            for (int nt = 0; nt < 4; nt++)
                acc[i + 4][nt] = __builtin_amdgcn_mfma_f32_16x16x32_bf16(af[i], bfr[nt], acc[i + 4][nt], 0, 0, 0);
        __builtin_amdgcn_s_setprio(0);
        __builtin_amdgcn_s_barrier();
        __builtin_amdgcn_sched_barrier(0);   // pin next iter's stages below this barrier

        cur++; if (cur == 3) cur = 0;
    }
#undef ST32

    if (n0 < 1024) {
#pragma unroll
        for (int mt = 0; mt < 8; mt++) {
#pragma unroll
            for (int nt = 0; nt < 4; nt++) {
                int col = n0 + (wn << 6) + (nt << 4) + lr;
                size_t rbase = (size_t)(m0 + (wm << 7) + (mt << 4) + (lg << 2));
#pragma unroll
                for (int r = 0; r < 4; r++)
                    kb[(rbase + r) * 1024 + col] = f2bf(acc[mt][nt][r]);
            }
        }
    } else {
#pragma unroll
        for (int mt = 0; mt < 8; mt++) {
#pragma unroll
            for (int nt = 0; nt < 4; nt++) {
                int dg = n0 - 1024 + (wn << 6) + (nt << 4) + lr;
                int rbase = m0 + (wm << 7) + (mt << 4) + (lg << 2);
                int bm = rbase >> 10, j = rbase & 1023;
                u16x4 o;
                o.x = f2bf(acc[mt][nt][0]); o.y = f2bf(acc[mt][nt][1]);
                o.z = f2bf(acc[mt][nt][2]); o.w = f2bf(acc[mt][nt][3]);
                *(u16x4*)(&vbT[((size_t)(bm << 10) + dg) * 1024 + j]) = o;
            }
        }
    }
}

// ---------------- fused flash attention over 1088 keys (unchanged) ----------------
__global__ __launch_bounds__(256) void attn_kernel(const unsigned short* __restrict__ qg, int qstride,
                                                   const unsigned short* __restrict__ kb,
                                                   const unsigned short* __restrict__ vbT,
                                                   const unsigned short* __restrict__ lkg, int lstride,
                                                   const unsigned short* __restrict__ lvT,
                                                   unsigned short* __restrict__ og) {
    __shared__ unsigned short K_lds[64 * 72];
    __shared__ unsigned short V_lds[64 * 72];
    __shared__ unsigned short P_lds[4][16 * 72];
    int bm = blockIdx.x >> 4, h = blockIdx.x & 15;
    int tid = threadIdx.x, lane = tid & 63, w = tid >> 6;
    int lr = lane & 15, lg = lane >> 4;

    bf16x8 qf[2];
#pragma unroll
    for (int kk = 0; kk < 2; kk++)
        qf[kk] = *(const bf16x8*)(qg + (size_t)((w << 4) + lr) * qstride + (h << 6) + (kk << 5) + (lg << 3));

    f32x4 acc[4] = {};
    float m_run[4], l_run[4];
#pragma unroll
    for (int r = 0; r < 4; r++) { m_run[r] = -1e30f; l_run[r] = 0.0f; }

    int jrow = tid >> 2;
    int seg = (tid & 3) << 4;

    const unsigned short* k_s = kb + (size_t)((bm << 10) + jrow) * 1024 + (h << 6) + seg;
    const unsigned short* v_s = vbT + (size_t)((bm << 10) + (h << 6) + jrow) * 1024 + seg;
    u16x8 k0 = *(const u16x8*)(k_s);
    u16x8 k1 = *(const u16x8*)(k_s + 8);
    u16x8 v0 = *(const u16x8*)(v_s);
    u16x8 v1 = *(const u16x8*)(v_s + 8);

    for (int t = 0; t < 17; t++) {
        *(u16x8*)(&K_lds[jrow * 72 + seg]) = k0;
        *(u16x8*)(&K_lds[jrow * 72 + seg + 8]) = k1;
        *(u16x8*)(&V_lds[jrow * 72 + seg]) = v0;
        *(u16x8*)(&V_lds[jrow * 72 + seg + 8]) = v1;
        __syncthreads();

        u16x8 nk0 = k0, nk1 = k1, nv0 = v0, nv1 = v1;
        if (t < 16) {
            if (t < 15) {
                const unsigned short* ks = kb + (size_t)((bm << 10) + ((t + 1) << 6) + jrow) * 1024 + (h << 6) + seg;
                const unsigned short* vs = vbT + (size_t)((bm << 10) + (h << 6) + jrow) * 1024 + ((t + 1) << 6) + seg;
                nk0 = *(const u16x8*)(ks);
                nk1 = *(const u16x8*)(ks + 8);
                nv0 = *(const u16x8*)(vs);
                nv1 = *(const u16x8*)(vs + 8);
            } else {
                const unsigned short* ks = lkg + (size_t)jrow * lstride + (h << 6) + seg;
                const unsigned short* vs = lvT + (size_t)((h << 6) + jrow) * 64 + seg;
                nk0 = *(const u16x8*)(ks);
                nk1 = *(const u16x8*)(ks + 8);
                nv0 = *(const u16x8*)(vs);
                nv1 = *(const u16x8*)(vs + 8);
            }
        }

        f32x4 s[4] = {};
#pragma unroll
        for (int jt = 0; jt < 4; jt++) {
#pragma unroll
            for (int kk = 0; kk < 2; kk++) {
                bf16x8 kf = *(const bf16x8*)(&K_lds[(size_t)((jt << 4) + lr) * 72 + (kk << 5) + (lg << 3)]);
                s[jt] = __builtin_amdgcn_mfma_f32_16x16x32_bf16(qf[kk], kf, s[jt], 0, 0, 0);
            }
        }
#pragma unroll
        for (int r = 0; r < 4; r++) {
            float mx = fmaxf(fmaxf(s[0][r], s[1][r]), fmaxf(s[2][r], s[3][r]));
            mx = fmaxf(mx, __shfl_xor(mx, 1));
            mx = fmaxf(mx, __shfl_xor(mx, 2));
            mx = fmaxf(mx, __shfl_xor(mx, 4));
            mx = fmaxf(mx, __shfl_xor(mx, 8));
            float nm = fmaxf(m_run[r], mx);
            float fct = __expf(m_run[r] - nm);
            m_run[r] = nm;
            float p0 = __expf(s[0][r] - nm);
            float p1 = __expf(s[1][r] - nm);
            float p2 = __expf(s[2][r] - nm);
            float p3 = __expf(s[3][r] - nm);
            float sum = p0 + p1 + p2 + p3;
            sum += __shfl_xor(sum, 1);
            sum += __shfl_xor(sum, 2);
            sum += __shfl_xor(sum, 4);
            sum += __shfl_xor(sum, 8);
            l_run[r] = l_run[r] * fct + sum;
#pragma unroll
            for (int dt = 0; dt < 4; dt++) acc[dt][r] *= fct;
            int prow = ((lg << 2) + r) * 72;
            P_lds[w][prow + lr]      = f2bf(p0);
            P_lds[w][prow + 16 + lr] = f2bf(p1);
            P_lds[w][prow + 32 + lr] = f2bf(p2);
            P_lds[w][prow + 48 + lr] = f2bf(p3);
        }
#pragma unroll
        for (int jkk = 0; jkk < 2; jkk++) {
            bf16x8 pf = *(const bf16x8*)(&P_lds[w][(size_t)lr * 72 + (jkk << 5) + (lg << 3)]);
#pragma unroll
            for (int dt = 0; dt < 4; dt++) {
                bf16x8 vf = *(const bf16x8*)(&V_lds[(size_t)((dt << 4) + lr) * 72 + (jkk << 5) + (lg << 3)]);
                acc[dt] = __builtin_amdgcn_mfma_f32_16x16x32_bf16(pf, vf, acc[dt], 0, 0, 0);
            }
        }
        __syncthreads();
        k0 = nk0; k1 = nk1; v0 = nv0; v1 = nv1;
    }
#pragma unroll
    for (int dt = 0; dt < 4; dt++) {
#pragma unroll
        for (int r = 0; r < 4; r++) {
            int i = (w << 4) + (lg << 2) + r;
            float v = acc[dt][r] / l_run[r];
            og[(size_t)((bm << 6) + i) * 1024 + (h << 6) + (dt << 4) + lr] = f2bf(v);
        }
    }
}

extern "C" void kernel_launch(void* const* d_in, const int* in_sizes, int n_in,
                              void* d_out, int out_size, void* d_ws, size_t ws_size,
                              hipStream_t stream) {
    const float* x       = (const float*)d_in[0];
    const float* latents = (const float*)d_in[1];
    const float* Wq      = (const float*)d_in[2];
    const float* Wkv     = (const float*)d_in[3];
    const float* Wout    = (const float*)d_in[4];
    const float* bout    = (const float*)d_in[5];
    char* ws = (char*)d_ws;
    unsigned short* xb    = (unsigned short*)(ws);                 // 64 MiB  [32768][1024]
    unsigned short* kb    = (unsigned short*)(ws + 67108864);      // 64 MiB  [32768][1024]
    unsigned short* vbT   = (unsigned short*)(ws + 134217728);     // 64 MiB  [32][1024 dg][1024 j]
    unsigned short* wqkvt = (unsigned short*)(ws + 201326592);     // 6 MiB   [3072][1024]
    unsigned short* wkvt  = wqkvt + 1024 * 1024;                   //         rows 1024..3071
    unsigned short* woutt = (unsigned short*)(ws + 207618048);     // 2 MiB   [1024][1024]
    unsigned short* latb  = (unsigned short*)(ws + 209715200);     // 128 KiB [64][1024]
    unsigned short* qlkvb = (unsigned short*)(ws + 209846272);     // 384 KiB [64][3072] (q | lk | --)
    unsigned short* attnb = (unsigned short*)(ws + 210239488);     // 4 MiB   [2048][1024]
    unsigned short* lvT   = (unsigned short*)(ws + 214433792);     // 128 KiB [1024 d2][64 j]

    // 1) all input conversions/transposes in one launch
    prep<<<6208, 256, 0, stream>>>(x, latents, Wq, Wkv, Wout, xb, latb, wqkvt, wkvt, woutt);
    // 2) qlkv gemm (24 blocks) + dominant kv gemm (1024 blocks) in one launch
    mega<<<1048, 512, 0, stream>>>(latb, wqkvt, qlkvb, lvT, xb, wkvt, kb, vbT, 32768, 2048, 1024);
    // 3) fused attention
    attn_kernel<<<512, 256, 0, stream>>>(qlkvb, 3072, kb, vbT, qlkvb + 1024, 3072, lvT, attnb);
    // 4) out = attnout @ Wout + bout (fp32 out)
    gemm128p<<<128, 256, 0, stream>>>(attnb, woutt, (void*)d_out, bout, nullptr, 2048, 1024, 1024, 1.0f, 0, 1, 1 << 30);
}

// Round 14
// 241.584 us; speedup vs baseline: 1.0814x; 1.0814x over previous
//
#include <hip/hip_runtime.h>
#include <cstdint>

typedef __attribute__((ext_vector_type(8))) __bf16 bf16x8;
typedef __attribute__((ext_vector_type(4))) float f32x4;
typedef __attribute__((ext_vector_type(8))) unsigned short u16x8;
typedef __attribute__((ext_vector_type(4))) unsigned short u16x4;

__device__ __forceinline__ unsigned short f2bf(float f) {
    union { float f; unsigned u; } v; v.f = f;
    unsigned u = v.u;
    return (unsigned short)((u + 0x7FFFu + ((u >> 16) & 1u)) >> 16);
}

__device__ __forceinline__ void gload_lds16(const void* g, void* l) {
    auto gp = reinterpret_cast<__attribute__((address_space(1))) unsigned*>(
        reinterpret_cast<uintptr_t>(g));
    auto lp = reinterpret_cast<__attribute__((address_space(3))) unsigned*>(
        reinterpret_cast<uintptr_t>(l));
    __builtin_amdgcn_global_load_lds(gp, lp, 16, 0, 0);
}

// ---------------- fused prep: cvt x | cvt latents | W transposes (one launch) ----------------
__global__ __launch_bounds__(256) void prep(const float* __restrict__ x,
                                            const float* __restrict__ latents,
                                            const float* __restrict__ Wq,
                                            const float* __restrict__ Wkv,
                                            const float* __restrict__ Wout,
                                            unsigned short* __restrict__ xb,
                                            unsigned short* __restrict__ latb,
                                            unsigned short* __restrict__ wqkvt,
                                            unsigned short* __restrict__ wkvt,
                                            unsigned short* __restrict__ woutt) {
    int b = blockIdx.x, tid = threadIdx.x;
    if (b < 2048) {                       // cvt x: 33554432 elems = 8388608 float4
        int idx = b * 256 + tid, stride = 2048 * 256;
        for (int i = idx; i < 8388608; i += stride) {
            float4 v = ((const float4*)x)[i];
            u16x4 o;
            o.x = f2bf(v.x); o.y = f2bf(v.y); o.z = f2bf(v.z); o.w = f2bf(v.w);
            ((u16x4*)xb)[i] = o;
        }
        return;
    }
    b -= 2048;
    if (b < 64) {                         // cvt latents: 16384 float4
        int i = b * 256 + tid;
        float4 v = ((const float4*)latents)[i];
        u16x4 o;
        o.x = f2bf(v.x); o.y = f2bf(v.y); o.z = f2bf(v.z); o.w = f2bf(v.w);
        ((u16x4*)latb)[i] = o;
        return;
    }
    b -= 64;
    const float* in; unsigned short* out; int R, C, bx, by;
    if (b < 1024)      { in = Wq;   out = wqkvt; R = 1024; C = 1024; bx = b & 31; by = b >> 5; }
    else if (b < 3072) { int v = b - 1024; in = Wkv;  out = wkvt;  R = 1024; C = 2048; bx = v & 63; by = v >> 6; }
    else               { int v = b - 3072; in = Wout; out = woutt; R = 1024; C = 1024; bx = v & 31; by = v >> 5; }
    __shared__ float t[32][33];
    int c0 = bx * 32, r0 = by * 32;
    int tx = tid & 31, ty = tid >> 5;
    for (int i = ty; i < 32; i += 8)
        t[i][tx] = in[(size_t)(r0 + i) * C + c0 + tx];
    __syncthreads();
    for (int i = ty; i < 32; i += 8)
        out[(size_t)(c0 + i) * R + r0 + tx] = f2bf(t[tx][i]);
}

// ---------------- pipelined 128x128 bf16 GEMM body (triple-buffer, counted vmcnt) ----
// tid is a VIRTUAL 256-thread id (512-thread callers pass tid&255: waves 4-7 mirror 0-3 —
// duplicate DMA/stores of identical data to identical addresses, barrier-safe).
__device__ __forceinline__ void gemm128p_body(const unsigned short* __restrict__ A,
                                              const unsigned short* __restrict__ Bt,
                                              void* __restrict__ C,
                                              const float* __restrict__ bias,
                                              unsigned short* __restrict__ vT,
                                              int M, int N, int K, float scale, int split,
                                              int c_f32, int vstart,
                                              int tid, int bid, int nwg,
                                              unsigned short* ldsbuf) {
#define LDSP(bi, half) (ldsbuf + ((bi) * 2 + (half)) * 4096)
    int ntx = N >> 7;
    int swz = bid;
    if ((nwg & 7) == 0) { int cpx = nwg >> 3; swz = (bid & 7) * cpx + (bid >> 3); }
    int m0 = (swz / ntx) << 7, n0 = (swz % ntx) << 7;
    int lane = tid & 63, w = tid >> 6;
    int wm = w >> 1, wn = w & 1;
    int lr = lane & 15, lg = lane >> 4;
    int gq = lg ^ ((lr >> 1) & 3);
    int nkt = K >> 5;

    int arow = tid >> 2;
    int sgl = (tid & 3) ^ ((arow >> 1) & 3);
    int ra0 = m0 + arow;      if (ra0 > M - 1) ra0 = M - 1;
    int ra1 = m0 + 64 + arow; if (ra1 > M - 1) ra1 = M - 1;
    const unsigned short* a0 = A + (size_t)ra0 * K + (sgl << 3);
    const unsigned short* a1 = A + (size_t)ra1 * K + (sgl << 3);
    const unsigned short* b0 = Bt + (size_t)(n0 + arow) * K + (sgl << 3);
    const unsigned short* b1 = Bt + (size_t)(n0 + 64 + arow) * K + (sgl << 3);

    f32x4 acc[4][4] = {};

#define ST_A128(bi, kt) do { \
        gload_lds16(a0 + ((kt) << 5), LDSP(bi, 0) + (w << 9)); \
        gload_lds16(a1 + ((kt) << 5), LDSP(bi, 0) + 2048 + (w << 9)); } while (0)
#define ST_B128(bi, kt) do { \
        gload_lds16(b0 + ((kt) << 5), LDSP(bi, 1) + (w << 9)); \
        gload_lds16(b1 + ((kt) << 5), LDSP(bi, 1) + 2048 + (w << 9)); } while (0)

    ST_A128(0, 0); ST_B128(0, 0);
    ST_A128(1, 1); ST_B128(1, 1);

    int buf = 0;
    for (int t = 0; t < nkt; ++t) {
        asm volatile("s_waitcnt vmcnt(4) lgkmcnt(0)" ::: "memory");
        __builtin_amdgcn_sched_barrier(0);
        __builtin_amdgcn_s_barrier();
        __builtin_amdgcn_sched_barrier(0);
        int st = t + 2; if (st >= nkt) st = nkt - 1;
        int sbuf = buf + 2; if (sbuf >= 3) sbuf -= 3;
        ST_A128(sbuf, st);
        ST_B128(sbuf, st);
        const unsigned short* pa = LDSP(buf, 0) + ((wm << 6) + lr) * 32 + (gq << 3);
        const unsigned short* pb = LDSP(buf, 1) + ((wn << 6) + lr) * 32 + (gq << 3);
        bf16x8 af[4], bfr[4];
#pragma unroll
        for (int nt = 0; nt < 4; nt++) bfr[nt] = *(const bf16x8*)(pb + nt * 512);
#pragma unroll
        for (int mt = 0; mt < 4; mt++) af[mt] = *(const bf16x8*)(pa + mt * 512);
        __builtin_amdgcn_s_setprio(1);
#pragma unroll
        for (int mt = 0; mt < 4; mt++)
#pragma unroll
            for (int nt = 0; nt < 4; nt++)
                acc[mt][nt] = __builtin_amdgcn_mfma_f32_16x16x32_bf16(af[mt], bfr[nt], acc[mt][nt], 0, 0, 0);
        __builtin_amdgcn_s_setprio(0);
        buf++; if (buf == 3) buf = 0;
    }
#undef ST_A128
#undef ST_B128
#undef LDSP

#pragma unroll
    for (int mt = 0; mt < 4; mt++) {
#pragma unroll
        for (int nt = 0; nt < 4; nt++) {
            int col = n0 + (wn << 6) + (nt << 4) + lr;
            float sc = (col < split) ? scale : 1.0f;
            float bv = bias ? bias[col] : 0.0f;
#pragma unroll
            for (int r = 0; r < 4; r++) {
                int row = m0 + (wm << 6) + (mt << 4) + (lg << 2) + r;
                if (row < M) {
                    float v = acc[mt][nt][r] * sc + bv;
                    if (vT && col >= vstart) vT[(size_t)(col - vstart) * 64 + row] = f2bf(v);
                    else if (c_f32) ((float*)C)[(size_t)row * N + col] = v;
                    else ((unsigned short*)C)[(size_t)row * N + col] = f2bf(v);
                }
            }
        }
    }
}

__global__ __launch_bounds__(256) void gemm128p(const unsigned short* __restrict__ A,
                                                const unsigned short* __restrict__ Bt,
                                                void* __restrict__ C,
                                                const float* __restrict__ bias,
                                                unsigned short* __restrict__ vT,
                                                int M, int N, int K, float scale, int split,
                                                int c_f32, int vstart) {
    __shared__ unsigned short lds[3 * 2 * 4096];
    gemm128p_body(A, Bt, C, bias, vT, M, N, K, scale, split, c_f32, vstart,
                  threadIdx.x, blockIdx.x, gridDim.x, lds);
}

// ---------------- mega: [0,24) qlkv gemm | [24,1048) 256x256 BK=64 GEMM ----------------
// Best-verified structure (r11, 240.4 µs total): 8-phase dbuf=2, counted vmcnt(4),
// relaxed interior drains (compiler-managed ds_read->MFMA waits); race-guard seams:
// P0 vmcnt(4)+barrier (tile publish), P3 lgkmcnt(0)+barrier (read-completion publish).
__global__ __launch_bounds__(512, 2) void mega(const unsigned short* __restrict__ latb,
                                               const unsigned short* __restrict__ wqkvt,
                                               unsigned short* __restrict__ qlkvb,
                                               unsigned short* __restrict__ lvT,
                                               const unsigned short* __restrict__ A,
                                               const unsigned short* __restrict__ Bt,
                                               unsigned short* __restrict__ kb,
                                               unsigned short* __restrict__ vbT,
                                               int M, int N, int K) {
    __shared__ unsigned short lds[2][32768];  // 128 KiB

    if (blockIdx.x < 24) {
        gemm128p_body(latb, wqkvt, qlkvb, nullptr, lvT, 64, 3072, 1024, 0.125f, 1024, 0, 2048,
                      threadIdx.x & 255, blockIdx.x, 24, &lds[0][0]);
        return;
    }

    int nkt = K >> 6;
    int ntx = N >> 8;
    int nwg = (M >> 8) * (N >> 8);
    int bid = blockIdx.x - 24, swz = bid;
    if ((nwg & 7) == 0) { int cpx = nwg >> 3; swz = (bid & 7) * cpx + (bid >> 3); }
    int m0 = (swz / ntx) << 8, n0 = (swz % ntx) << 8;
    int tid = threadIdx.x, lane = tid & 63, w = tid >> 6;
    int wm = w >> 2, wn = w & 3;
    int lr = lane & 15, lg = lane >> 4;

    int srow = lane >> 3;
    int sg = (lane & 7) ^ srow;
    const unsigned short* aS = A + (size_t)(m0 + (w << 3) + srow) * K + (sg << 3);
    const unsigned short* bS = Bt + (size_t)(n0 + (w << 3) + srow) * K + (sg << 3);
    size_t rs64 = (size_t)64 * K;

    int baseA = (wm << 13) + lr * 64;
    int baseB = 16384 + (wn << 12) + lr * 64;
    int kg0 = (((0 << 2) + lg) ^ (lr & 7)) << 3;
    int kg1 = (((1 << 2) + lg) ^ (lr & 7)) << 3;

    f32x4 acc[8][4] = {};

#define ST_A(bi, kt) do { \
        gload_lds16(aS + ((size_t)(kt) << 6),          &lds[bi][(w << 9)]); \
        gload_lds16(aS + rs64 + ((size_t)(kt) << 6),   &lds[bi][4096 + (w << 9)]); \
        gload_lds16(aS + 2*rs64 + ((size_t)(kt) << 6), &lds[bi][8192 + (w << 9)]); \
        gload_lds16(aS + 3*rs64 + ((size_t)(kt) << 6), &lds[bi][12288 + (w << 9)]); } while (0)
#define ST_B(bi, kt) do { \
        gload_lds16(bS + ((size_t)(kt) << 6),          &lds[bi][16384 + (w << 9)]); \
        gload_lds16(bS + rs64 + ((size_t)(kt) << 6),   &lds[bi][20480 + (w << 9)]); \
        gload_lds16(bS + 2*rs64 + ((size_t)(kt) << 6), &lds[bi][24576 + (w << 9)]); \
        gload_lds16(bS + 3*rs64 + ((size_t)(kt) << 6), &lds[bi][28672 + (w << 9)]); } while (0)

    ST_A(0, 0);
    ST_B(0, 0);

    for (int t = 0; t < nkt; ++t) {
        int cur = t & 1, nxt = cur ^ 1;
        int st = t + 1; if (st >= nkt) st = nkt - 1;
        const unsigned short* L = &lds[cur][0];
        bf16x8 af[4], bfr[4];

        // ---- P0: stage A(t+1); vmcnt(4) publishes tile t; reads + MFMA (compiler waits) ----
        ST_A(nxt, st);
        __builtin_amdgcn_sched_barrier(0);
        asm volatile("s_waitcnt vmcnt(4)" ::: "memory");
        __builtin_amdgcn_sched_barrier(0);
        __builtin_amdgcn_s_barrier();
        __builtin_amdgcn_sched_barrier(0);
#pragma unroll
        for (int nt = 0; nt < 4; nt++) bfr[nt] = *(const bf16x8*)(L + baseB + nt * 1024 + kg0);
#pragma unroll
        for (int i = 0; i < 4; i++) af[i] = *(const bf16x8*)(L + baseA + i * 1024 + kg0);
        __builtin_amdgcn_s_setprio(1);
#pragma unroll
        for (int i = 0; i < 4; i++)
#pragma unroll
            for (int nt = 0; nt < 4; nt++)
                acc[i][nt] = __builtin_amdgcn_mfma_f32_16x16x32_bf16(af[i], bfr[nt], acc[i][nt], 0, 0, 0);
        __builtin_amdgcn_s_setprio(0);

        // ---- P1: stage B(t+1); reads ks0 m4-7; MFMA ----
        ST_B(nxt, st);
#pragma unroll
        for (int i = 0; i < 4; i++) af[i] = *(const bf16x8*)(L + baseA + (i + 4) * 1024 + kg0);
        __builtin_amdgcn_s_setprio(1);
#pragma unroll
        for (int i = 0; i < 4; i++)
#pragma unroll
            for (int nt = 0; nt < 4; nt++)
                acc[i + 4][nt] = __builtin_amdgcn_mfma_f32_16x16x32_bf16(af[i], bfr[nt], acc[i + 4][nt], 0, 0, 0);
        __builtin_amdgcn_s_setprio(0);

        // ---- P2: reads ks1 m0-3 + B ks1; MFMA ----
#pragma unroll
        for (int nt = 0; nt < 4; nt++) bfr[nt] = *(const bf16x8*)(L + baseB + nt * 1024 + kg1);
#pragma unroll
        for (int i = 0; i < 4; i++) af[i] = *(const bf16x8*)(L + baseA + i * 1024 + kg1);
        __builtin_amdgcn_s_setprio(1);
#pragma unroll
        for (int i = 0; i < 4; i++)
#pragma unroll
            for (int nt = 0; nt < 4; nt++)
                acc[i][nt] = __builtin_amdgcn_mfma_f32_16x16x32_bf16(af[i], bfr[nt], acc[i][nt], 0, 0, 0);
        __builtin_amdgcn_s_setprio(0);

        // ---- P3: reads ks1 m4-7; lgkmcnt(0)+barrier = read-completion seam; MFMA ----
#pragma unroll
        for (int i = 0; i < 4; i++) af[i] = *(const bf16x8*)(L + baseA + (i + 4) * 1024 + kg1);
        asm volatile("s_waitcnt lgkmcnt(0)" ::: "memory");
        __builtin_amdgcn_sched_barrier(0);
        __builtin_amdgcn_s_barrier();
        __builtin_amdgcn_sched_barrier(0);
        __builtin_amdgcn_s_setprio(1);
#pragma unroll
        for (int i = 0; i < 4; i++)
#pragma unroll
            for (int nt = 0; nt < 4; nt++)
                acc[i + 4][nt] = __builtin_amdgcn_mfma_f32_16x16x32_bf16(af[i], bfr[nt], acc[i + 4][nt], 0, 0, 0);
        __builtin_amdgcn_s_setprio(0);
    }
#undef ST_A
#undef ST_B

    if (n0 < 1024) {
#pragma unroll
        for (int mt = 0; mt < 8; mt++) {
#pragma unroll
            for (int nt = 0; nt < 4; nt++) {
                int col = n0 + (wn << 6) + (nt << 4) + lr;
                size_t rbase = (size_t)(m0 + (wm << 7) + (mt << 4) + (lg << 2));
#pragma unroll
                for (int r = 0; r < 4; r++)
                    kb[(rbase + r) * 1024 + col] = f2bf(acc[mt][nt][r]);
            }
        }
    } else {
#pragma unroll
        for (int mt = 0; mt < 8; mt++) {
#pragma unroll
            for (int nt = 0; nt < 4; nt++) {
                int dg = n0 - 1024 + (wn << 6) + (nt << 4) + lr;
                int rbase = m0 + (wm << 7) + (mt << 4) + (lg << 2);
                int bm = rbase >> 10, j = rbase & 1023;
                u16x4 o;
                o.x = f2bf(acc[mt][nt][0]); o.y = f2bf(acc[mt][nt][1]);
                o.z = f2bf(acc[mt][nt][2]); o.w = f2bf(acc[mt][nt][3]);
                *(u16x4*)(&vbT[((size_t)(bm << 10) + dg) * 1024 + j]) = o;
            }
        }
    }
}

// ---------------- fused flash attention over 1088 keys (unchanged) ----------------
__global__ __launch_bounds__(256) void attn_kernel(const unsigned short* __restrict__ qg, int qstride,
                                                   const unsigned short* __restrict__ kb,
                                                   const unsigned short* __restrict__ vbT,
                                                   const unsigned short* __restrict__ lkg, int lstride,
                                                   const unsigned short* __restrict__ lvT,
                                                   unsigned short* __restrict__ og) {
    __shared__ unsigned short K_lds[64 * 72];
    __shared__ unsigned short V_lds[64 * 72];
    __shared__ unsigned short P_lds[4][16 * 72];
    int bm = blockIdx.x >> 4, h = blockIdx.x & 15;
    int tid = threadIdx.x, lane = tid & 63, w = tid >> 6;
    int lr = lane & 15, lg = lane >> 4;

    bf16x8 qf[2];
#pragma unroll
    for (int kk = 0; kk < 2; kk++)
        qf[kk] = *(const bf16x8*)(qg + (size_t)((w << 4) + lr) * qstride + (h << 6) + (kk << 5) + (lg << 3));

    f32x4 acc[4] = {};
    float m_run[4], l_run[4];
#pragma unroll
    for (int r = 0; r < 4; r++) { m_run[r] = -1e30f; l_run[r] = 0.0f; }

    int jrow = tid >> 2;
    int seg = (tid & 3) << 4;

    const unsigned short* k_s = kb + (size_t)((bm << 10) + jrow) * 1024 + (h << 6) + seg;
    const unsigned short* v_s = vbT + (size_t)((bm << 10) + (h << 6) + jrow) * 1024 + seg;
    u16x8 k0 = *(const u16x8*)(k_s);
    u16x8 k1 = *(const u16x8*)(k_s + 8);
    u16x8 v0 = *(const u16x8*)(v_s);
    u16x8 v1 = *(const u16x8*)(v_s + 8);

    for (int t = 0; t < 17; t++) {
        *(u16x8*)(&K_lds[jrow * 72 + seg]) = k0;
        *(u16x8*)(&K_lds[jrow * 72 + seg + 8]) = k1;
        *(u16x8*)(&V_lds[jrow * 72 + seg]) = v0;
        *(u16x8*)(&V_lds[jrow * 72 + seg + 8]) = v1;
        __syncthreads();

        u16x8 nk0 = k0, nk1 = k1, nv0 = v0, nv1 = v1;
        if (t < 16) {
            if (t < 15) {
                const unsigned short* ks = kb + (size_t)((bm << 10) + ((t + 1) << 6) + jrow) * 1024 + (h << 6) + seg;
                const unsigned short* vs = vbT + (size_t)((bm << 10) + (h << 6) + jrow) * 1024 + ((t + 1) << 6) + seg;
                nk0 = *(const u16x8*)(ks);
                nk1 = *(const u16x8*)(ks + 8);
                nv0 = *(const u16x8*)(vs);
                nv1 = *(const u16x8*)(vs + 8);
            } else {
                const unsigned short* ks = lkg + (size_t)jrow * lstride + (h << 6) + seg;
                const unsigned short* vs = lvT + (size_t)((h << 6) + jrow) * 64 + seg;
                nk0 = *(const u16x8*)(ks);
                nk1 = *(const u16x8*)(ks + 8);
                nv0 = *(const u16x8*)(vs);
                nv1 = *(const u16x8*)(vs + 8);
            }
        }

        f32x4 s[4] = {};
#pragma unroll
        for (int jt = 0; jt < 4; jt++) {
#pragma unroll
            for (int kk = 0; kk < 2; kk++) {
                bf16x8 kf = *(const bf16x8*)(&K_lds[(size_t)((jt << 4) + lr) * 72 + (kk << 5) + (lg << 3)]);
                s[jt] = __builtin_amdgcn_mfma_f32_16x16x32_bf16(qf[kk], kf, s[jt], 0, 0, 0);
            }
        }
#pragma unroll
        for (int r = 0; r < 4; r++) {
            float mx = fmaxf(fmaxf(s[0][r], s[1][r]), fmaxf(s[2][r], s[3][r]));
            mx = fmaxf(mx, __shfl_xor(mx, 1));
            mx = fmaxf(mx, __shfl_xor(mx, 2));
            mx = fmaxf(mx, __shfl_xor(mx, 4));
            mx = fmaxf(mx, __shfl_xor(mx, 8));
            float nm = fmaxf(m_run[r], mx);
            float fct = __expf(m_run[r] - nm);
            m_run[r] = nm;
            float p0 = __expf(s[0][r] - nm);
            float p1 = __expf(s[1][r] - nm);
            float p2 = __expf(s[2][r] - nm);
            float p3 = __expf(s[3][r] - nm);
            float sum = p0 + p1 + p2 + p3;
            sum += __shfl_xor(sum, 1);
            sum += __shfl_xor(sum, 2);
            sum += __shfl_xor(sum, 4);
            sum += __shfl_xor(sum, 8);
            l_run[r] = l_run[r] * fct + sum;
#pragma unroll
            for (int dt = 0; dt < 4; dt++) acc[dt][r] *= fct;
            int prow = ((lg << 2) + r) * 72;
            P_lds[w][prow + lr]      = f2bf(p0);
            P_lds[w][prow + 16 + lr] = f2bf(p1);
            P_lds[w][prow + 32 + lr] = f2bf(p2);
            P_lds[w][prow + 48 + lr] = f2bf(p3);
        }
#pragma unroll
        for (int jkk = 0; jkk < 2; jkk++) {
            bf16x8 pf = *(const bf16x8*)(&P_lds[w][(size_t)lr * 72 + (jkk << 5) + (lg << 3)]);
#pragma unroll
            for (int dt = 0; dt < 4; dt++) {
                bf16x8 vf = *(const bf16x8*)(&V_lds[(size_t)((dt << 4) + lr) * 72 + (jkk << 5) + (lg << 3)]);
                acc[dt] = __builtin_amdgcn_mfma_f32_16x16x32_bf16(pf, vf, acc[dt], 0, 0, 0);
            }
        }
        __syncthreads();
        k0 = nk0; k1 = nk1; v0 = nv0; v1 = nv1;
    }
#pragma unroll
    for (int dt = 0; dt < 4; dt++) {
#pragma unroll
        for (int r = 0; r < 4; r++) {
            int i = (w << 4) + (lg << 2) + r;
            float v = acc[dt][r] / l_run[r];
            og[(size_t)((bm << 6) + i) * 1024 + (h << 6) + (dt << 4) + lr] = f2bf(v);
        }
    }
}

extern "C" void kernel_launch(void* const* d_in, const int* in_sizes, int n_in,
                              void* d_out, int out_size, void* d_ws, size_t ws_size,
                              hipStream_t stream) {
    const float* x       = (const float*)d_in[0];
    const float* latents = (const float*)d_in[1];
    const float* Wq      = (const float*)d_in[2];
    const float* Wkv     = (const float*)d_in[3];
    const float* Wout    = (const float*)d_in[4];
    const float* bout    = (const float*)d_in[5];
    char* ws = (char*)d_ws;
    unsigned short* xb    = (unsigned short*)(ws);                 // 64 MiB  [32768][1024]
    unsigned short* kb    = (unsigned short*)(ws + 67108864);      // 64 MiB  [32768][1024]
    unsigned short* vbT   = (unsigned short*)(ws + 134217728);     // 64 MiB  [32][1024 dg][1024 j]
    unsigned short* wqkvt = (unsigned short*)(ws + 201326592);     // 6 MiB   [3072][1024]
    unsigned short* wkvt  = wqkvt + 1024 * 1024;                   //         rows 1024..3071
    unsigned short* woutt = (unsigned short*)(ws + 207618048);     // 2 MiB   [1024][1024]
    unsigned short* latb  = (unsigned short*)(ws + 209715200);     // 128 KiB [64][1024]
    unsigned short* qlkvb = (unsigned short*)(ws + 209846272);     // 384 KiB [64][3072] (q | lk | --)
    unsigned short* attnb = (unsigned short*)(ws + 210239488);     // 4 MiB   [2048][1024]
    unsigned short* lvT   = (unsigned short*)(ws + 214433792);     // 128 KiB [1024 d2][64 j]

    // 1) all input conversions/transposes in one launch
    prep<<<6208, 256, 0, stream>>>(x, latents, Wq, Wkv, Wout, xb, latb, wqkvt, wkvt, woutt);
    // 2) qlkv gemm (24 blocks) + dominant kv gemm (1024 blocks) in one launch
    mega<<<1048, 512, 0, stream>>>(latb, wqkvt, qlkvb, lvT, xb, wkvt, kb, vbT, 32768, 2048, 1024);
    // 3) fused attention
    attn_kernel<<<512, 256, 0, stream>>>(qlkvb, 3072, kb, vbT, qlkvb + 1024, 3072, lvT, attnb);
    // 4) out = attnout @ Wout + bout (fp32 out)
    gemm128p<<<128, 256, 0, stream>>>(attnb, woutt, (void*)d_out, bout, nullptr, 2048, 1024, 1024, 1.0f, 0, 1, 1 << 30);
}

// Round 15
// 229.115 us; speedup vs baseline: 1.1402x; 1.0544x over previous
//
#include <hip/hip_runtime.h>
#include <cstdint>

typedef __attribute__((ext_vector_type(8))) __bf16 bf16x8;
typedef __attribute__((ext_vector_type(4))) float f32x4;
typedef __attribute__((ext_vector_type(8))) unsigned short u16x8;
typedef __attribute__((ext_vector_type(4))) unsigned short u16x4;

__device__ __forceinline__ unsigned short f2bf(float f) {
    union { float f; unsigned u; } v; v.f = f;
    unsigned u = v.u;
    return (unsigned short)((u + 0x7FFFu + ((u >> 16) & 1u)) >> 16);
}

__device__ __forceinline__ void gload_lds16(const void* g, void* l) {
    auto gp = reinterpret_cast<__attribute__((address_space(1))) unsigned*>(
        reinterpret_cast<uintptr_t>(g));
    auto lp = reinterpret_cast<__attribute__((address_space(3))) unsigned*>(
        reinterpret_cast<uintptr_t>(l));
    __builtin_amdgcn_global_load_lds(gp, lp, 16, 0, 0);
}

// ---------------- fused prep: cvt x | cvt latents | W transposes (one launch) ----------------
__global__ __launch_bounds__(256) void prep(const float* __restrict__ x,
                                            const float* __restrict__ latents,
                                            const float* __restrict__ Wq,
                                            const float* __restrict__ Wkv,
                                            const float* __restrict__ Wout,
                                            unsigned short* __restrict__ xb,
                                            unsigned short* __restrict__ latb,
                                            unsigned short* __restrict__ wqkvt,
                                            unsigned short* __restrict__ wkvt,
                                            unsigned short* __restrict__ woutt) {
    int b = blockIdx.x, tid = threadIdx.x;
    if (b < 2048) {                       // cvt x: 33554432 elems = 8388608 float4
        int idx = b * 256 + tid, stride = 2048 * 256;
        for (int i = idx; i < 8388608; i += stride) {
            float4 v = ((const float4*)x)[i];
            u16x4 o;
            o.x = f2bf(v.x); o.y = f2bf(v.y); o.z = f2bf(v.z); o.w = f2bf(v.w);
            ((u16x4*)xb)[i] = o;
        }
        return;
    }
    b -= 2048;
    if (b < 64) {                         // cvt latents: 16384 float4
        int i = b * 256 + tid;
        float4 v = ((const float4*)latents)[i];
        u16x4 o;
        o.x = f2bf(v.x); o.y = f2bf(v.y); o.z = f2bf(v.z); o.w = f2bf(v.w);
        ((u16x4*)latb)[i] = o;
        return;
    }
    b -= 64;
    const float* in; unsigned short* out; int R, C, bx, by;
    if (b < 1024)      { in = Wq;   out = wqkvt; R = 1024; C = 1024; bx = b & 31; by = b >> 5; }
    else if (b < 3072) { int v = b - 1024; in = Wkv;  out = wkvt;  R = 1024; C = 2048; bx = v & 63; by = v >> 6; }
    else               { int v = b - 3072; in = Wout; out = woutt; R = 1024; C = 1024; bx = v & 31; by = v >> 5; }
    __shared__ float t[32][33];
    int c0 = bx * 32, r0 = by * 32;
    int tx = tid & 31, ty = tid >> 5;
    for (int i = ty; i < 32; i += 8)
        t[i][tx] = in[(size_t)(r0 + i) * C + c0 + tx];
    __syncthreads();
    for (int i = ty; i < 32; i += 8)
        out[(size_t)(c0 + i) * R + r0 + tx] = f2bf(t[tx][i]);
}

// ---------------- pipelined 128x128 bf16 GEMM (triple-buffer, counted vmcnt) ----
__global__ __launch_bounds__(256) void gemm128p(const unsigned short* __restrict__ A,
                                                const unsigned short* __restrict__ Bt,
                                                void* __restrict__ C,
                                                const float* __restrict__ bias,
                                                int M, int N, int K, float scale, int split,
                                                int c_f32) {
    __shared__ unsigned short lds[3][2][4096];  // 48 KiB
    int ntx = N >> 7;
    int nwg = gridDim.x, bid = blockIdx.x, swz = bid;
    if ((nwg & 7) == 0) { int cpx = nwg >> 3; swz = (bid & 7) * cpx + (bid >> 3); }
    int m0 = (swz / ntx) << 7, n0 = (swz % ntx) << 7;
    int tid = threadIdx.x, lane = tid & 63, w = tid >> 6;
    int wm = w >> 1, wn = w & 1;
    int lr = lane & 15, lg = lane >> 4;
    int gq = lg ^ ((lr >> 1) & 3);
    int nkt = K >> 5;

    int arow = tid >> 2;
    int sgl = (tid & 3) ^ ((arow >> 1) & 3);
    int ra0 = m0 + arow;      if (ra0 > M - 1) ra0 = M - 1;
    int ra1 = m0 + 64 + arow; if (ra1 > M - 1) ra1 = M - 1;
    const unsigned short* a0 = A + (size_t)ra0 * K + (sgl << 3);
    const unsigned short* a1 = A + (size_t)ra1 * K + (sgl << 3);
    const unsigned short* b0 = Bt + (size_t)(n0 + arow) * K + (sgl << 3);
    const unsigned short* b1 = Bt + (size_t)(n0 + 64 + arow) * K + (sgl << 3);

    f32x4 acc[4][4] = {};

#define ST_A128(bi, kt) do { \
        gload_lds16(a0 + ((kt) << 5), &lds[bi][0][w << 9]); \
        gload_lds16(a1 + ((kt) << 5), &lds[bi][0][2048 + (w << 9)]); } while (0)
#define ST_B128(bi, kt) do { \
        gload_lds16(b0 + ((kt) << 5), &lds[bi][1][w << 9]); \
        gload_lds16(b1 + ((kt) << 5), &lds[bi][1][2048 + (w << 9)]); } while (0)

    ST_A128(0, 0); ST_B128(0, 0);
    ST_A128(1, 1); ST_B128(1, 1);

    int buf = 0;
    for (int t = 0; t < nkt; ++t) {
        asm volatile("s_waitcnt vmcnt(4) lgkmcnt(0)" ::: "memory");
        __builtin_amdgcn_sched_barrier(0);
        __builtin_amdgcn_s_barrier();
        __builtin_amdgcn_sched_barrier(0);
        int st = t + 2; if (st >= nkt) st = nkt - 1;
        int sbuf = buf + 2; if (sbuf >= 3) sbuf -= 3;
        ST_A128(sbuf, st);
        ST_B128(sbuf, st);
        const unsigned short* pa = &lds[buf][0][((wm << 6) + lr) * 32 + (gq << 3)];
        const unsigned short* pb = &lds[buf][1][((wn << 6) + lr) * 32 + (gq << 3)];
        bf16x8 af[4], bfr[4];
#pragma unroll
        for (int nt = 0; nt < 4; nt++) bfr[nt] = *(const bf16x8*)(pb + nt * 512);
#pragma unroll
        for (int mt = 0; mt < 4; mt++) af[mt] = *(const bf16x8*)(pa + mt * 512);
        __builtin_amdgcn_s_setprio(1);
#pragma unroll
        for (int mt = 0; mt < 4; mt++)
#pragma unroll
            for (int nt = 0; nt < 4; nt++)
                acc[mt][nt] = __builtin_amdgcn_mfma_f32_16x16x32_bf16(af[mt], bfr[nt], acc[mt][nt], 0, 0, 0);
        __builtin_amdgcn_s_setprio(0);
        buf++; if (buf == 3) buf = 0;
    }
#undef ST_A128
#undef ST_B128

#pragma unroll
    for (int mt = 0; mt < 4; mt++) {
#pragma unroll
        for (int nt = 0; nt < 4; nt++) {
            int col = n0 + (wn << 6) + (nt << 4) + lr;
            float sc = (col < split) ? scale : 1.0f;
            float bv = bias ? bias[col] : 0.0f;
#pragma unroll
            for (int r = 0; r < 4; r++) {
                int row = m0 + (wm << 6) + (mt << 4) + (lg << 2) + r;
                if (row < M) {
                    float v = acc[mt][nt][r] * sc + bv;
                    if (c_f32) ((float*)C)[(size_t)row * N + col] = v;
                    else       ((unsigned short*)C)[(size_t)row * N + col] = f2bf(v);
                }
            }
        }
    }
}

// ---------------- mega: 1024 kv-GEMM blocks (perfect 4-round packing) ----------------
// r11-verified 256x256 BK=64 8-phase dbuf=2 counted-vmcnt structure. qlkv is no longer
// separate blocks (24 thin blocks added a +13 µs makespan tail: 1048 blocks broke the
// exact 4x256 dispatch quantization). Instead blocks 0..191 compute one 64x16 qlkv
// column-sliver as a cheap epilogue: 8 waves split K (128 each, 16 MFMA + L2-hot
// gathers), LDS reduction (after vmcnt(0)+barrier drain of in-flight gload_lds).
__global__ __launch_bounds__(512, 2) void mega(const unsigned short* __restrict__ latb,
                                               const unsigned short* __restrict__ wqkvt,
                                               unsigned short* __restrict__ qlkvb,
                                               unsigned short* __restrict__ lvT,
                                               const unsigned short* __restrict__ A,
                                               const unsigned short* __restrict__ Bt,
                                               unsigned short* __restrict__ kb,
                                               unsigned short* __restrict__ vbT,
                                               int M, int N, int K) {
    __shared__ __attribute__((aligned(16))) unsigned short lds[2][32768];  // 128 KiB

    int nkt = K >> 6;
    int ntx = N >> 8;
    int nwg = gridDim.x;
    int bid = blockIdx.x, swz = bid;
    if ((nwg & 7) == 0) { int cpx = nwg >> 3; swz = (bid & 7) * cpx + (bid >> 3); }
    int m0 = (swz / ntx) << 8, n0 = (swz % ntx) << 8;
    int tid = threadIdx.x, lane = tid & 63, w = tid >> 6;
    int wm = w >> 2, wn = w & 3;
    int lr = lane & 15, lg = lane >> 4;

    int srow = lane >> 3;
    int sg = (lane & 7) ^ srow;
    const unsigned short* aS = A + (size_t)(m0 + (w << 3) + srow) * K + (sg << 3);
    const unsigned short* bS = Bt + (size_t)(n0 + (w << 3) + srow) * K + (sg << 3);
    size_t rs64 = (size_t)64 * K;

    int baseA = (wm << 13) + lr * 64;
    int baseB = 16384 + (wn << 12) + lr * 64;
    int kg0 = (((0 << 2) + lg) ^ (lr & 7)) << 3;
    int kg1 = (((1 << 2) + lg) ^ (lr & 7)) << 3;

    f32x4 acc[8][4] = {};

#define ST_A(bi, kt) do { \
        gload_lds16(aS + ((size_t)(kt) << 6),          &lds[bi][(w << 9)]); \
        gload_lds16(aS + rs64 + ((size_t)(kt) << 6),   &lds[bi][4096 + (w << 9)]); \
        gload_lds16(aS + 2*rs64 + ((size_t)(kt) << 6), &lds[bi][8192 + (w << 9)]); \
        gload_lds16(aS + 3*rs64 + ((size_t)(kt) << 6), &lds[bi][12288 + (w << 9)]); } while (0)
#define ST_B(bi, kt) do { \
        gload_lds16(bS + ((size_t)(kt) << 6),          &lds[bi][16384 + (w << 9)]); \
        gload_lds16(bS + rs64 + ((size_t)(kt) << 6),   &lds[bi][20480 + (w << 9)]); \
        gload_lds16(bS + 2*rs64 + ((size_t)(kt) << 6), &lds[bi][24576 + (w << 9)]); \
        gload_lds16(bS + 3*rs64 + ((size_t)(kt) << 6), &lds[bi][28672 + (w << 9)]); } while (0)

    ST_A(0, 0);
    ST_B(0, 0);

    for (int t = 0; t < nkt; ++t) {
        int cur = t & 1, nxt = cur ^ 1;
        int st = t + 1; if (st >= nkt) st = nkt - 1;
        const unsigned short* L = &lds[cur][0];
        bf16x8 af[4], bfr[4];

        // ---- P0: stage A(t+1); vmcnt(4) publishes tile t; reads + MFMA (compiler waits) ----
        ST_A(nxt, st);
        __builtin_amdgcn_sched_barrier(0);
        asm volatile("s_waitcnt vmcnt(4)" ::: "memory");
        __builtin_amdgcn_sched_barrier(0);
        __builtin_amdgcn_s_barrier();
        __builtin_amdgcn_sched_barrier(0);
#pragma unroll
        for (int nt = 0; nt < 4; nt++) bfr[nt] = *(const bf16x8*)(L + baseB + nt * 1024 + kg0);
#pragma unroll
        for (int i = 0; i < 4; i++) af[i] = *(const bf16x8*)(L + baseA + i * 1024 + kg0);
        __builtin_amdgcn_s_setprio(1);
#pragma unroll
        for (int i = 0; i < 4; i++)
#pragma unroll
            for (int nt = 0; nt < 4; nt++)
                acc[i][nt] = __builtin_amdgcn_mfma_f32_16x16x32_bf16(af[i], bfr[nt], acc[i][nt], 0, 0, 0);
        __builtin_amdgcn_s_setprio(0);

        // ---- P1: stage B(t+1); reads ks0 m4-7; MFMA ----
        ST_B(nxt, st);
#pragma unroll
        for (int i = 0; i < 4; i++) af[i] = *(const bf16x8*)(L + baseA + (i + 4) * 1024 + kg0);
        __builtin_amdgcn_s_setprio(1);
#pragma unroll
        for (int i = 0; i < 4; i++)
#pragma unroll
            for (int nt = 0; nt < 4; nt++)
                acc[i + 4][nt] = __builtin_amdgcn_mfma_f32_16x16x32_bf16(af[i], bfr[nt], acc[i + 4][nt], 0, 0, 0);
        __builtin_amdgcn_s_setprio(0);

        // ---- P2: reads ks1 m0-3 + B ks1; MFMA ----
#pragma unroll
        for (int nt = 0; nt < 4; nt++) bfr[nt] = *(const bf16x8*)(L + baseB + nt * 1024 + kg1);
#pragma unroll
        for (int i = 0; i < 4; i++) af[i] = *(const bf16x8*)(L + baseA + i * 1024 + kg1);
        __builtin_amdgcn_s_setprio(1);
#pragma unroll
        for (int i = 0; i < 4; i++)
#pragma unroll
            for (int nt = 0; nt < 4; nt++)
                acc[i][nt] = __builtin_amdgcn_mfma_f32_16x16x32_bf16(af[i], bfr[nt], acc[i][nt], 0, 0, 0);
        __builtin_amdgcn_s_setprio(0);

        // ---- P3: reads ks1 m4-7; lgkmcnt(0)+barrier = read-completion seam; MFMA ----
#pragma unroll
        for (int i = 0; i < 4; i++) af[i] = *(const bf16x8*)(L + baseA + (i + 4) * 1024 + kg1);
        asm volatile("s_waitcnt lgkmcnt(0)" ::: "memory");
        __builtin_amdgcn_sched_barrier(0);
        __builtin_amdgcn_s_barrier();
        __builtin_amdgcn_sched_barrier(0);
        __builtin_amdgcn_s_setprio(1);
#pragma unroll
        for (int i = 0; i < 4; i++)
#pragma unroll
            for (int nt = 0; nt < 4; nt++)
                acc[i + 4][nt] = __builtin_amdgcn_mfma_f32_16x16x32_bf16(af[i], bfr[nt], acc[i + 4][nt], 0, 0, 0);
        __builtin_amdgcn_s_setprio(0);
    }
#undef ST_A
#undef ST_B

    if (n0 < 1024) {
#pragma unroll
        for (int mt = 0; mt < 8; mt++) {
#pragma unroll
            for (int nt = 0; nt < 4; nt++) {
                int col = n0 + (wn << 6) + (nt << 4) + lr;
                size_t rbase = (size_t)(m0 + (wm << 7) + (mt << 4) + (lg << 2));
#pragma unroll
                for (int r = 0; r < 4; r++)
                    kb[(rbase + r) * 1024 + col] = f2bf(acc[mt][nt][r]);
            }
        }
    } else {
#pragma unroll
        for (int mt = 0; mt < 8; mt++) {
#pragma unroll
            for (int nt = 0; nt < 4; nt++) {
                int dg = n0 - 1024 + (wn << 6) + (nt << 4) + lr;
                int rbase = m0 + (wm << 7) + (mt << 4) + (lg << 2);
                int bm = rbase >> 10, j = rbase & 1023;
                u16x4 o;
                o.x = f2bf(acc[mt][nt][0]); o.y = f2bf(acc[mt][nt][1]);
                o.z = f2bf(acc[mt][nt][2]); o.w = f2bf(acc[mt][nt][3]);
                *(u16x4*)(&vbT[((size_t)(bm << 10) + dg) * 1024 + j]) = o;
            }
        }
    }

    // ---- qlkv micro-epilogue: blocks 0..191 compute cols [16*bid, 16*bid+16) of
    // [q | lk | lv] = latb[64][1024] @ wqkvt[3072][1024]^T (split-K over 8 waves) ----
    if (bid < 192) {
        int col0 = bid << 4;
        f32x4 qa[4] = {};
        int kbase = w << 7;  // wave's K-slice [128w, 128w+128)
#pragma unroll
        for (int ks = 0; ks < 4; ks++) {
            int k = kbase + (ks << 5) + (lg << 3);
            bf16x8 bf = *(const bf16x8*)(wqkvt + (size_t)(col0 + lr) * 1024 + k);
#pragma unroll
            for (int mt = 0; mt < 4; mt++) {
                bf16x8 afr = *(const bf16x8*)(latb + (size_t)((mt << 4) + lr) * 1024 + k);
                qa[mt] = __builtin_amdgcn_mfma_f32_16x16x32_bf16(afr, bf, qa[mt], 0, 0, 0);
            }
        }
        // reuse LDS for cross-wave reduction: drain in-flight gload_lds first
        asm volatile("s_waitcnt vmcnt(0)" ::: "memory");
        __builtin_amdgcn_s_barrier();
        f32x4* red = (f32x4*)&lds[0][0];  // 8 waves x 4 mtiles x 64 lanes x 16B = 32 KiB
#pragma unroll
        for (int mt = 0; mt < 4; mt++) red[((w << 2) + mt) * 64 + lane] = qa[mt];
        __syncthreads();
        if (w < 4) {  // wave w sums partials for mtile w
            f32x4 s = red[(w) * 64 + lane];
#pragma unroll
            for (int ww = 1; ww < 8; ww++) s += red[((ww << 2) + w) * 64 + lane];
            int col = col0 + lr;
            float sc = (col < 1024) ? 0.125f : 1.0f;
#pragma unroll
            for (int r = 0; r < 4; r++) {
                int row = (w << 4) + (lg << 2) + r;
                float v = s[r] * sc;
                if (col >= 2048) lvT[(size_t)(col - 2048) * 64 + row] = f2bf(v);
                else             qlkvb[(size_t)row * 3072 + col] = f2bf(v);
            }
        }
    }
}

// ---------------- fused flash attention over 1088 keys (unchanged) ----------------
__global__ __launch_bounds__(256) void attn_kernel(const unsigned short* __restrict__ qg, int qstride,
                                                   const unsigned short* __restrict__ kb,
                                                   const unsigned short* __restrict__ vbT,
                                                   const unsigned short* __restrict__ lkg, int lstride,
                                                   const unsigned short* __restrict__ lvT,
                                                   unsigned short* __restrict__ og) {
    __shared__ unsigned short K_lds[64 * 72];
    __shared__ unsigned short V_lds[64 * 72];
    __shared__ unsigned short P_lds[4][16 * 72];
    int bm = blockIdx.x >> 4, h = blockIdx.x & 15;
    int tid = threadIdx.x, lane = tid & 63, w = tid >> 6;
    int lr = lane & 15, lg = lane >> 4;

    bf16x8 qf[2];
#pragma unroll
    for (int kk = 0; kk < 2; kk++)
        qf[kk] = *(const bf16x8*)(qg + (size_t)((w << 4) + lr) * qstride + (h << 6) + (kk << 5) + (lg << 3));

    f32x4 acc[4] = {};
    float m_run[4], l_run[4];
#pragma unroll
    for (int r = 0; r < 4; r++) { m_run[r] = -1e30f; l_run[r] = 0.0f; }

    int jrow = tid >> 2;
    int seg = (tid & 3) << 4;

    const unsigned short* k_s = kb + (size_t)((bm << 10) + jrow) * 1024 + (h << 6) + seg;
    const unsigned short* v_s = vbT + (size_t)((bm << 10) + (h << 6) + jrow) * 1024 + seg;
    u16x8 k0 = *(const u16x8*)(k_s);
    u16x8 k1 = *(const u16x8*)(k_s + 8);
    u16x8 v0 = *(const u16x8*)(v_s);
    u16x8 v1 = *(const u16x8*)(v_s + 8);

    for (int t = 0; t < 17; t++) {
        *(u16x8*)(&K_lds[jrow * 72 + seg]) = k0;
        *(u16x8*)(&K_lds[jrow * 72 + seg + 8]) = k1;
        *(u16x8*)(&V_lds[jrow * 72 + seg]) = v0;
        *(u16x8*)(&V_lds[jrow * 72 + seg + 8]) = v1;
        __syncthreads();

        u16x8 nk0 = k0, nk1 = k1, nv0 = v0, nv1 = v1;
        if (t < 16) {
            if (t < 15) {
                const unsigned short* ks = kb + (size_t)((bm << 10) + ((t + 1) << 6) + jrow) * 1024 + (h << 6) + seg;
                const unsigned short* vs = vbT + (size_t)((bm << 10) + (h << 6) + jrow) * 1024 + ((t + 1) << 6) + seg;
                nk0 = *(const u16x8*)(ks);
                nk1 = *(const u16x8*)(ks + 8);
                nv0 = *(const u16x8*)(vs);
                nv1 = *(const u16x8*)(vs + 8);
            } else {
                const unsigned short* ks = lkg + (size_t)jrow * lstride + (h << 6) + seg;
                const unsigned short* vs = lvT + (size_t)((h << 6) + jrow) * 64 + seg;
                nk0 = *(const u16x8*)(ks);
                nk1 = *(const u16x8*)(ks + 8);
                nv0 = *(const u16x8*)(vs);
                nv1 = *(const u16x8*)(vs + 8);
            }
        }

        f32x4 s[4] = {};
#pragma unroll
        for (int jt = 0; jt < 4; jt++) {
#pragma unroll
            for (int kk = 0; kk < 2; kk++) {
                bf16x8 kf = *(const bf16x8*)(&K_lds[(size_t)((jt << 4) + lr) * 72 + (kk << 5) + (lg << 3)]);
                s[jt] = __builtin_amdgcn_mfma_f32_16x16x32_bf16(qf[kk], kf, s[jt], 0, 0, 0);
            }
        }
#pragma unroll
        for (int r = 0; r < 4; r++) {
            float mx = fmaxf(fmaxf(s[0][r], s[1][r]), fmaxf(s[2][r], s[3][r]));
            mx = fmaxf(mx, __shfl_xor(mx, 1));
            mx = fmaxf(mx, __shfl_xor(mx, 2));
            mx = fmaxf(mx, __shfl_xor(mx, 4));
            mx = fmaxf(mx, __shfl_xor(mx, 8));
            float nm = fmaxf(m_run[r], mx);
            float fct = __expf(m_run[r] - nm);
            m_run[r] = nm;
            float p0 = __expf(s[0][r] - nm);
            float p1 = __expf(s[1][r] - nm);
            float p2 = __expf(s[2][r] - nm);
            float p3 = __expf(s[3][r] - nm);
            float sum = p0 + p1 + p2 + p3;
            sum += __shfl_xor(sum, 1);
            sum += __shfl_xor(sum, 2);
            sum += __shfl_xor(sum, 4);
            sum += __shfl_xor(sum, 8);
            l_run[r] = l_run[r] * fct + sum;
#pragma unroll
            for (int dt = 0; dt < 4; dt++) acc[dt][r] *= fct;
            int prow = ((lg << 2) + r) * 72;
            P_lds[w][prow + lr]      = f2bf(p0);
            P_lds[w][prow + 16 + lr] = f2bf(p1);
            P_lds[w][prow + 32 + lr] = f2bf(p2);
            P_lds[w][prow + 48 + lr] = f2bf(p3);
        }
#pragma unroll
        for (int jkk = 0; jkk < 2; jkk++) {
            bf16x8 pf = *(const bf16x8*)(&P_lds[w][(size_t)lr * 72 + (jkk << 5) + (lg << 3)]);
#pragma unroll
            for (int dt = 0; dt < 4; dt++) {
                bf16x8 vf = *(const bf16x8*)(&V_lds[(size_t)((dt << 4) + lr) * 72 + (jkk << 5) + (lg << 3)]);
                acc[dt] = __builtin_amdgcn_mfma_f32_16x16x32_bf16(pf, vf, acc[dt], 0, 0, 0);
            }
        }
        __syncthreads();
        k0 = nk0; k1 = nk1; v0 = nv0; v1 = nv1;
    }
#pragma unroll
    for (int dt = 0; dt < 4; dt++) {
#pragma unroll
        for (int r = 0; r < 4; r++) {
            int i = (w << 4) + (lg << 2) + r;
            float v = acc[dt][r] / l_run[r];
            og[(size_t)((bm << 6) + i) * 1024 + (h << 6) + (dt << 4) + lr] = f2bf(v);
        }
    }
}

extern "C" void kernel_launch(void* const* d_in, const int* in_sizes, int n_in,
                              void* d_out, int out_size, void* d_ws, size_t ws_size,
                              hipStream_t stream) {
    const float* x       = (const float*)d_in[0];
    const float* latents = (const float*)d_in[1];
    const float* Wq      = (const float*)d_in[2];
    const float* Wkv     = (const float*)d_in[3];
    const float* Wout    = (const float*)d_in[4];
    const float* bout    = (const float*)d_in[5];
    char* ws = (char*)d_ws;
    unsigned short* xb    = (unsigned short*)(ws);                 // 64 MiB  [32768][1024]
    unsigned short* kb    = (unsigned short*)(ws + 67108864);      // 64 MiB  [32768][1024]
    unsigned short* vbT   = (unsigned short*)(ws + 134217728);     // 64 MiB  [32][1024 dg][1024 j]
    unsigned short* wqkvt = (unsigned short*)(ws + 201326592);     // 6 MiB   [3072][1024]
    unsigned short* wkvt  = wqkvt + 1024 * 1024;                   //         rows 1024..3071
    unsigned short* woutt = (unsigned short*)(ws + 207618048);     // 2 MiB   [1024][1024]
    unsigned short* latb  = (unsigned short*)(ws + 209715200);     // 128 KiB [64][1024]
    unsigned short* qlkvb = (unsigned short*)(ws + 209846272);     // 384 KiB [64][3072] (q | lk | --)
    unsigned short* attnb = (unsigned short*)(ws + 210239488);     // 4 MiB   [2048][1024]
    unsigned short* lvT   = (unsigned short*)(ws + 214433792);     // 128 KiB [1024 d2][64 j]

    // 1) all input conversions/transposes in one launch
    prep<<<6208, 256, 0, stream>>>(x, latents, Wq, Wkv, Wout, xb, latb, wqkvt, wkvt, woutt);
    // 2) kv gemm (exactly 1024 blocks = 4 dispatch rounds) + qlkv as spread micro-epilogue
    mega<<<1024, 512, 0, stream>>>(latb, wqkvt, qlkvb, lvT, xb, wkvt, kb, vbT, 32768, 2048, 1024);
    // 3) fused attention
    attn_kernel<<<512, 256, 0, stream>>>(qlkvb, 3072, kb, vbT, qlkvb + 1024, 3072, lvT, attnb);
    // 4) out = attnout @ Wout + bout (fp32 out)
    gemm128p<<<128, 256, 0, stream>>>(attnb, woutt, (void*)d_out, bout, 2048, 1024, 1024, 1.0f, 0, 1);
}